// Round 4
// baseline (141.021 us; speedup 1.0000x reference)
//
#include <hip/hip_runtime.h>

// uLSIF loss: out = mean_i[ -2*exp(x_i.a_i/T) + (sum_j exp(2*x_i.a_j/T) - exp(2*x_i.a_i/T))/(N-1) ]
// N=8192, D=128, T=128.
// S1,S3: exact fp32/f64 diagonal, fused into the fp32->f16 convert pass (single read of x,a).
// S2: fused f16-MFMA GEMM (8192x8192x128) with exp2+sum epilogue; sim never materialized.
// f16 (not bf16) inputs: 8x lower rounding error (~1e-4 rel on output), same MFMA rate.

#define NN 8192
#define DD 128

typedef __attribute__((ext_vector_type(4))) float f32x4;
typedef __attribute__((ext_vector_type(8))) _Float16 f16x8;

__device__ __forceinline__ void gload_lds16(const void* g, void* l) {
    __builtin_amdgcn_global_load_lds(
        (const __attribute__((address_space(1))) void*)g,
        (__attribute__((address_space(3))) void*)l, 16, 0, 0);
}

// ---------------- zero accumulators (ws is poisoned 0xAA before every launch) ----
__global__ void zero_kernel(double* acc) {
    acc[0] = 0.0;  // S2
    acc[1] = 0.0;  // S1
    acc[2] = 0.0;  // S3
}

// ---------------- fused fp32->f16 convert + exact diagonal ----------------------
// 1024 blocks x 256 threads; thread i handles float4 index i of BOTH x and a
// (8 rows per block, 32 threads per row). Diagonal dot in fp32, exp in f64.
__global__ void conv_diag_kernel(const float4* __restrict__ x, const float4* __restrict__ a,
                                 ushort4* __restrict__ xb, ushort4* __restrict__ ab,
                                 double* __restrict__ acc) {
    int t = threadIdx.x;
    int i = blockIdx.x * 256 + t;                 // 0..262143
    float4 xv = x[i];
    float4 av = a[i];
    ushort4 xu, au;
    xu.x = __builtin_bit_cast(unsigned short, (_Float16)xv.x);
    xu.y = __builtin_bit_cast(unsigned short, (_Float16)xv.y);
    xu.z = __builtin_bit_cast(unsigned short, (_Float16)xv.z);
    xu.w = __builtin_bit_cast(unsigned short, (_Float16)xv.w);
    au.x = __builtin_bit_cast(unsigned short, (_Float16)av.x);
    au.y = __builtin_bit_cast(unsigned short, (_Float16)av.y);
    au.z = __builtin_bit_cast(unsigned short, (_Float16)av.z);
    au.w = __builtin_bit_cast(unsigned short, (_Float16)av.w);
    xb[i] = xu;
    ab[i] = au;

    // per-row diagonal dot: 32 consecutive threads cover one row (32 x 4 = 128)
    float d = xv.x * av.x + xv.y * av.y + xv.z * av.z + xv.w * av.w;
#pragma unroll
    for (int off = 16; off > 0; off >>= 1) d += __shfl_down(d, off, 32);

    __shared__ double rr[8];
    if ((t & 31) == 0) rr[t >> 5] = exp((double)d * (1.0 / 128.0));
    __syncthreads();
    if (t == 0) {
        double s1 = 0.0, s3 = 0.0;
#pragma unroll
        for (int k = 0; k < 8; ++k) { s1 += rr[k]; s3 += rr[k] * rr[k]; }
        atomicAdd(&acc[1], s1);
        atomicAdd(&acc[2], s3);
    }
}

// ---------------- fused GEMM + exp2 + sum ----------------------------------------
// 128x128 tile, K=128 single shot. 4 waves (2x2), each wave 64x64 via 4x4
// fragments of mfma_f32_16x16x32_f16. LDS 2x32KB, st-swizzle (row&7)<<4 applied
// on the *global source* (linear global_load_lds dest) and on ds_read addresses.
__global__ __launch_bounds__(256) void gemm_exp_sum(const ushort* __restrict__ xb,
                                                    const ushort* __restrict__ ab,
                                                    double* __restrict__ acc) {
    __shared__ char smem[65536];
    char* As = smem;
    char* Bs = smem + 32768;

    const int t    = threadIdx.x;
    const int lane = t & 63;
    const int wid  = t >> 6;
    const int tm   = blockIdx.x >> 6;   // 64 row tiles
    const int tn   = blockIdx.x & 63;   // 64 col tiles

    // tile spans full K=D: each 128x128 f16 tile is one contiguous 32KB block
    const char* gA = (const char*)(xb + (size_t)tm * 128 * DD);
    const char* gB = (const char*)(ab + (size_t)tn * 128 * DD);

    // ---- stage global -> LDS (8 issues x 4KB per matrix), pre-swizzled source ----
    {
        const int L = t * 16;
        char* ldsA = As + wid * 1024;   // wave-uniform base; HW adds lane*16
        char* ldsB = Bs + wid * 1024;
#pragma unroll
        for (int i = 0; i < 8; ++i) {
            int off = i * 4096 + L;                 // linear dest byte offset
            int row = off >> 8;                     // 256 B per row
            int cb  = off & 255;
            int src = (row << 8) | (cb ^ ((row & 7) << 4));
            gload_lds16(gA + src, ldsA + i * 4096);
            gload_lds16(gB + src, ldsB + i * 4096);
        }
    }
    asm volatile("s_waitcnt vmcnt(0)" ::: "memory");
    __syncthreads();

    // ---- compute: wave (wr,wc) owns 64x64; 4x4 fragments; 4 k-steps of 32 ----
    const int wr = (wid >> 1) * 64;
    const int wc = (wid & 1) * 64;
    const int rl = lane & 15;
    const int kq = (lane >> 4) * 16;   // byte offset of this lane's 8 f16 within k-step

    f32x4 acc_[4][4];
#pragma unroll
    for (int mi = 0; mi < 4; ++mi)
#pragma unroll
        for (int ni = 0; ni < 4; ++ni)
            acc_[mi][ni] = f32x4{0.f, 0.f, 0.f, 0.f};

#pragma unroll
    for (int ks = 0; ks < 4; ++ks) {
        const int cb = ks * 64 + kq;
        f16x8 af[4], bfr[4];
#pragma unroll
        for (int mi = 0; mi < 4; ++mi) {
            int r = wr + mi * 16 + rl;
            af[mi] = *(const f16x8*)(As + r * 256 + (cb ^ ((r & 7) << 4)));
        }
#pragma unroll
        for (int ni = 0; ni < 4; ++ni) {
            int r = wc + ni * 16 + rl;
            bfr[ni] = *(const f16x8*)(Bs + r * 256 + (cb ^ ((r & 7) << 4)));
        }
#pragma unroll
        for (int mi = 0; mi < 4; ++mi)
#pragma unroll
            for (int ni = 0; ni < 4; ++ni)
                acc_[mi][ni] = __builtin_amdgcn_mfma_f32_16x16x32_f16(
                    af[mi], bfr[ni], acc_[mi][ni], 0, 0, 0);
    }

    // ---- epilogue: sum exp(2*s/T) = exp2(s / (64*ln2)) over the tile ----
    const float C2 = (float)(2.0 / (128.0 * 0.69314718055994530942));
    float lsum = 0.f;
#pragma unroll
    for (int mi = 0; mi < 4; ++mi)
#pragma unroll
        for (int ni = 0; ni < 4; ++ni)
#pragma unroll
            for (int q = 0; q < 4; ++q)
                lsum += __builtin_amdgcn_exp2f(acc_[mi][ni][q] * C2);

#pragma unroll
    for (int off = 32; off > 0; off >>= 1) lsum += __shfl_down(lsum, off);

    __syncthreads();                    // done reading LDS fragments; reuse smem
    float* red = (float*)smem;
    if (lane == 0) red[wid] = lsum;
    __syncthreads();
    if (t == 0) {
        double bs = (double)red[0] + (double)red[1] + (double)red[2] + (double)red[3];
        atomicAdd(&acc[0], bs);
    }
}

// ---------------- finalize -------------------------------------------------------
__global__ void finalize_kernel(const double* __restrict__ acc, float* __restrict__ out) {
    double res = (-2.0 * acc[1] + (acc[0] - acc[2]) / (double)(NN - 1)) / (double)NN;
    out[0] = (float)res;
}

extern "C" void kernel_launch(void* const* d_in, const int* in_sizes, int n_in,
                              void* d_out, int out_size, void* d_ws, size_t ws_size,
                              hipStream_t stream) {
    const float* x = (const float*)d_in[0];
    const float* a = (const float*)d_in[1];
    float* out = (float*)d_out;
    char* ws = (char*)d_ws;

    double* acc = (double*)ws;                                  // 3 doubles
    ushort* xb  = (ushort*)(ws + 256);                          // 2 MB f16 x
    ushort* ab  = (ushort*)(ws + 256 + (size_t)NN * DD * 2);    // 2 MB f16 a

    zero_kernel<<<1, 1, 0, stream>>>(acc);
    conv_diag_kernel<<<1024, 256, 0, stream>>>((const float4*)x, (const float4*)a,
                                               (ushort4*)xb, (ushort4*)ab, acc);
    gemm_exp_sum<<<4096, 256, 0, stream>>>(xb, ab, acc);
    finalize_kernel<<<1, 1, 0, stream>>>(acc, out);
}

// Round 5
// 83.191 us; speedup vs baseline: 1.6951x; 1.6951x over previous
//
#include <hip/hip_runtime.h>

// uLSIF loss: out = mean_i[ -2*exp(x_i.a_i/T) + (sum_j exp(2*x_i.a_j/T) - exp(2*x_i.a_i/T))/(N-1) ]
// N=8192, D=128, T=128.
// conv_diag: fp32->f16 convert (a pre-scaled by C2=2/(T*ln2)) + exact fp32/f64 diagonal,
//            per-block partials (NO same-address atomics).
// gemm: 256 blocks x 512 thr, 8 waves. Each block: 256 A-rows reg-cached (staged once),
//       8 B-tiles of 128 cols streamed through a double-buffered 2x32KB LDS with
//       counted vmcnt(4) prefetch (T3/T4). exp2+sum epilogue per tile; per-block partial.
// finalize: one block sums all partials.

#define NN 8192
#define DD 128
#define NT 8   // B-tiles per block: 8192 cols / 128 cols-per-tile / 8 chunks

typedef __attribute__((ext_vector_type(4))) float f32x4;
typedef __attribute__((ext_vector_type(8))) _Float16 f16x8;

__device__ __forceinline__ void gload_lds16(const void* g, void* l) {
    __builtin_amdgcn_global_load_lds(
        (const __attribute__((address_space(1))) void*)g,
        (__attribute__((address_space(3))) void*)l, 16, 0, 0);
}

// raw barrier with compiler memory fence (no vmcnt/lgkmcnt drain)
__device__ __forceinline__ void block_sync() {
    asm volatile("" ::: "memory");
    __builtin_amdgcn_s_barrier();
    asm volatile("" ::: "memory");
}

// ---------------- fused fp32->f16 convert + exact diagonal -----------------------
// 1024 blocks x 256 threads; thread i handles float4 index i of BOTH x and a.
// a is pre-scaled by C2 so the GEMM accumulator is directly the exp2 argument.
__global__ void conv_diag_kernel(const float4* __restrict__ x, const float4* __restrict__ a,
                                 ushort4* __restrict__ xb, ushort4* __restrict__ ab,
                                 double* __restrict__ s1p, double* __restrict__ s3p) {
    const float C2 = (float)(2.0 / (128.0 * 0.69314718055994530942));
    int t = threadIdx.x;
    int i = blockIdx.x * 256 + t;                 // 0..262143
    float4 xv = x[i];
    float4 av = a[i];
    ushort4 xu, au;
    xu.x = __builtin_bit_cast(unsigned short, (_Float16)xv.x);
    xu.y = __builtin_bit_cast(unsigned short, (_Float16)xv.y);
    xu.z = __builtin_bit_cast(unsigned short, (_Float16)xv.z);
    xu.w = __builtin_bit_cast(unsigned short, (_Float16)xv.w);
    au.x = __builtin_bit_cast(unsigned short, (_Float16)(av.x * C2));
    au.y = __builtin_bit_cast(unsigned short, (_Float16)(av.y * C2));
    au.z = __builtin_bit_cast(unsigned short, (_Float16)(av.z * C2));
    au.w = __builtin_bit_cast(unsigned short, (_Float16)(av.w * C2));
    xb[i] = xu;
    ab[i] = au;

    // per-row diagonal dot in exact fp32: 32 consecutive threads per row
    float d = xv.x * av.x + xv.y * av.y + xv.z * av.z + xv.w * av.w;  // note: uses RAW a? no:
    // av here is raw fp32 a (unscaled) -- scaling only applied to the f16 store above.
#pragma unroll
    for (int off = 16; off > 0; off >>= 1) d += __shfl_down(d, off, 32);

    __shared__ double rr[8];
    if ((t & 31) == 0) rr[t >> 5] = exp((double)d * (1.0 / 128.0));
    __syncthreads();
    if (t == 0) {
        double s1 = 0.0, s3 = 0.0;
#pragma unroll
        for (int k = 0; k < 8; ++k) { s1 += rr[k]; s3 += rr[k] * rr[k]; }
        s1p[blockIdx.x] = s1;
        s3p[blockIdx.x] = s3;
    }
}

// ---------------- fused GEMM + exp2 + sum ----------------------------------------
// grid = 32 row-tiles x 8 col-chunks = 256 blocks, 512 threads (8 waves, 4m x 2n).
// LDS: A 64KB [0,64K) staged once; B dbuf 2x32KB [64K,128K).
// Swizzle: linear LDS dest, source XOR (row&7)<<4, same XOR on ds_read (rule #21).
__global__ __launch_bounds__(512, 2) void gemm_exp_sum(const ushort* __restrict__ xb,
                                                       const ushort* __restrict__ ab,
                                                       double* __restrict__ s2p) {
    __shared__ char smem[131072];
    char* As    = smem;
    char* Bbuf  = smem + 65536;

    const int tid  = threadIdx.x;
    const int lane = tid & 63;
    const int wid  = tid >> 6;          // 0..7
    const int bm    = blockIdx.x >> 3;  // 32 row tiles of 256
    const int chunk = blockIdx.x & 7;   // 8 column chunks

    const char* gA  = (const char*)(xb + (size_t)bm * 256 * DD);
    const char* gB0 = (const char*)(ab + (size_t)chunk * (NT * 128) * DD);

    const int t16 = tid * 16;

    // ---- prologue: stage A (64KB, 8 issues) + B tile0 (32KB, 4 issues) ----
    {
        char* ldsA = As + wid * 1024;
#pragma unroll
        for (int i = 0; i < 8; ++i) {
            int off = i * 8192 + t16;
            int row = off >> 8;
            int src = (row << 8) | ((off & 255) ^ ((row & 7) << 4));
            gload_lds16(gA + src, ldsA + i * 8192);
        }
        char* ldsB = Bbuf + wid * 1024;
#pragma unroll
        for (int i = 0; i < 4; ++i) {
            int off = i * 8192 + t16;
            int row = off >> 8;
            int src = (row << 8) | ((off & 255) ^ ((row & 7) << 4));
            gload_lds16(gB0 + src, ldsB + i * 8192);
        }
    }
    asm volatile("s_waitcnt vmcnt(4)" ::: "memory");   // A done (B0's 4 may remain)
    block_sync();

    // ---- load A fragments into registers (live across all tiles) ----
    const int wr = (wid >> 1) * 64;     // 4 m-waves: 0,64,128,192
    const int wc = (wid & 1) * 64;      // 2 n-waves: 0,64
    const int rl = lane & 15;
    const int kq = (lane >> 4) * 16;    // byte offset of this lane's 8 f16 in k-step
    f16x8 af[4][4];
#pragma unroll
    for (int mi = 0; mi < 4; ++mi)
#pragma unroll
        for (int ks = 0; ks < 4; ++ks) {
            int r  = wr + mi * 16 + rl;
            int cb = ks * 64 + kq;
            af[mi][ks] = *(const f16x8*)(As + r * 256 + (cb ^ ((r & 7) << 4)));
        }

    float ls0 = 0.f, ls1 = 0.f, ls2 = 0.f, ls3 = 0.f;

    // ---- main loop over NT B-tiles, double-buffered, counted vmcnt ----
#pragma unroll
    for (int t = 0; t < NT; ++t) {
        const char* Bs = Bbuf + (t & 1) * 32768;

        if (t + 1 < NT) {               // prefetch next tile into other half
            const char* gB  = gB0 + (size_t)(t + 1) * 128 * DD * 2;
            char* ldsB = Bbuf + ((t + 1) & 1) * 32768 + wid * 1024;
#pragma unroll
            for (int i = 0; i < 4; ++i) {
                int off = i * 8192 + t16;
                int row = off >> 8;
                int src = (row << 8) | ((off & 255) ^ ((row & 7) << 4));
                gload_lds16(gB + src, ldsB + i * 8192);
            }
            asm volatile("s_waitcnt vmcnt(4)" ::: "memory");  // tile t landed
        } else {
            asm volatile("s_waitcnt vmcnt(0)" ::: "memory");
        }
        block_sync();                   // all waves see tile t

        f32x4 acc[4][4];
#pragma unroll
        for (int mi = 0; mi < 4; ++mi)
#pragma unroll
            for (int ni = 0; ni < 4; ++ni)
                acc[mi][ni] = f32x4{0.f, 0.f, 0.f, 0.f};

#pragma unroll
        for (int ks = 0; ks < 4; ++ks) {
            f16x8 bfr[4];
#pragma unroll
            for (int ni = 0; ni < 4; ++ni) {
                int r  = wc + ni * 16 + rl;
                int cb = ks * 64 + kq;
                bfr[ni] = *(const f16x8*)(Bs + r * 256 + (cb ^ ((r & 7) << 4)));
            }
#pragma unroll
            for (int mi = 0; mi < 4; ++mi)
#pragma unroll
                for (int ni = 0; ni < 4; ++ni)
                    acc[mi][ni] = __builtin_amdgcn_mfma_f32_16x16x32_f16(
                        af[mi][ks], bfr[ni], acc[mi][ni], 0, 0, 0);
        }

        // epilogue: acc already holds 2*s/T/ln2 (a pre-scaled) -> pure exp2 + add
#pragma unroll
        for (int mi = 0; mi < 4; ++mi)
#pragma unroll
            for (int ni = 0; ni < 4; ++ni) {
                ls0 += __builtin_amdgcn_exp2f(acc[mi][ni][0]);
                ls1 += __builtin_amdgcn_exp2f(acc[mi][ni][1]);
                ls2 += __builtin_amdgcn_exp2f(acc[mi][ni][2]);
                ls3 += __builtin_amdgcn_exp2f(acc[mi][ni][3]);
            }

        block_sync();                   // tile t fully consumed before overwrite
    }

    float lsum = (ls0 + ls1) + (ls2 + ls3);
#pragma unroll
    for (int off = 32; off > 0; off >>= 1) lsum += __shfl_down(lsum, off);

    double* wred = (double*)smem;       // A region is dead now
    if (lane == 0) wred[wid] = (double)lsum;
    __syncthreads();
    if (tid == 0) {
        double s = 0.0;
#pragma unroll
        for (int k = 0; k < 8; ++k) s += wred[k];
        s2p[blockIdx.x] = s;
    }
}

// ---------------- finalize: sum all partials -------------------------------------
__global__ void finalize_kernel(const double* __restrict__ s1p, const double* __restrict__ s3p,
                                const double* __restrict__ s2p, float* __restrict__ out) {
    int t = threadIdx.x;                // 1024 threads
    double v1 = s1p[t];
    double v3 = s3p[t];
    double v2 = (t < 256) ? s2p[t] : 0.0;
#pragma unroll
    for (int off = 32; off > 0; off >>= 1) {
        v1 += __shfl_down(v1, off);
        v3 += __shfl_down(v3, off);
        v2 += __shfl_down(v2, off);
    }
    __shared__ double r1[16], r2[16], r3[16];
    int wid = t >> 6, lane = t & 63;
    if (lane == 0) { r1[wid] = v1; r2[wid] = v2; r3[wid] = v3; }
    __syncthreads();
    if (t == 0) {
        double S1 = 0.0, S2 = 0.0, S3 = 0.0;
#pragma unroll
        for (int k = 0; k < 16; ++k) { S1 += r1[k]; S2 += r2[k]; S3 += r3[k]; }
        double res = (-2.0 * S1 + (S2 - S3) / (double)(NN - 1)) / (double)NN;
        out[0] = (float)res;
    }
}

extern "C" void kernel_launch(void* const* d_in, const int* in_sizes, int n_in,
                              void* d_out, int out_size, void* d_ws, size_t ws_size,
                              hipStream_t stream) {
    const float* x = (const float*)d_in[0];
    const float* a = (const float*)d_in[1];
    float* out = (float*)d_out;
    char* ws = (char*)d_ws;

    double* s1p = (double*)ws;                      // 1024 f64 = 8 KB
    double* s3p = (double*)(ws + 8192);             // 1024 f64 = 8 KB
    double* s2p = (double*)(ws + 16384);            // 256  f64 = 2 KB
    ushort* xb  = (ushort*)(ws + 32768);            // 2 MB f16 x
    ushort* ab  = (ushort*)(ws + 32768 + (size_t)NN * DD * 2);  // 2 MB f16 a*C2

    conv_diag_kernel<<<1024, 256, 0, stream>>>((const float4*)x, (const float4*)a,
                                               (ushort4*)xb, (ushort4*)ab, s1p, s3p);
    gemm_exp_sum<<<256, 512, 0, stream>>>(xb, ab, s2p);
    finalize_kernel<<<1, 1024, 0, stream>>>(s1p, s3p, s2p, out);
}